// Round 4
// baseline (6749.052 us; speedup 1.0000x reference)
//
#include <hip/hip_runtime.h>
#include <hip/hip_bf16.h>
#include <math.h>

#define PH   264
#define NPIX (PH*PH)          // 69696
#define HPIX (NPIX/2)         // 34848 pixel pairs per image
#define NBAT 16
#define NIMG (NBAT*64)        // 1024
#define NLAY 4

typedef unsigned short ushort_t;
typedef unsigned int   uint_t;

// bf16 helpers for the INTERNAL H buffer only (all external I/O is fp32)
__device__ __forceinline__ float blo(uint_t u){ union{uint_t u; float f;} v; v.u = u << 16;        return v.f; }
__device__ __forceinline__ float bhi(uint_t u){ union{uint_t u; float f;} v; v.u = u & 0xffff0000u; return v.f; }
__device__ __forceinline__ ushort_t f2b(float f){
  __hip_bfloat16 h = __float2bfloat16(f);
  union{__hip_bfloat16 h; ushort_t s;} v; v.h = h; return v.s;
}
__device__ __forceinline__ uint_t pack2(float a, float b){
  return (uint_t)f2b(a) | ((uint_t)f2b(b) << 16);
}
__device__ __forceinline__ float gelu_f(float v){
  return v*0.5f*(1.0f + erff(v*0.70710678118654752f));
}

// DFT twiddle tables (fp32, exact integer-mod phase)
__global__ __launch_bounds__(256) void k_tables(float* __restrict__ tFT, float* __restrict__ tCT,
                                                float* __restrict__ tST, float* __restrict__ tYc,
                                                float* __restrict__ tYs){
  int idx = blockIdx.x*256 + threadIdx.x;
  const double W0 = 6.283185307179586 / 264.0;
  if (idx < 8448){                       // tFT[y*32+kk]: kk=2k -> cos, 2k+1 -> -sin (e^{-i 2pi k y/264})
    int y = idx >> 5, kk = idx & 31, k = kk >> 1;
    int ph = (k*y) % 264;
    float ang = (float)(W0 * ph), s, c;
    sincosf(ang, &s, &c);
    tFT[idx] = (kk & 1) ? -s : c;
  } else if (idx < 16896){               // tCT/tST[x*32+kxi]: cos/sin(2pi kxe x/264), kxe in [-16,15]
    int d = idx - 8448;
    int x = d >> 5, kxi = d & 31;
    int kxe = (kxi < 16) ? kxi : kxi - 32;
    int ph = ((kxe*x) % 264 + 264) % 264;
    float ang = (float)(W0 * ph), s, c;
    sincosf(ang, &s, &c);
    tCT[d] = c; tST[d] = s;
  } else if (idx < 16896 + 4224){        // tYc/tYs[k*264+y]
    int d = idx - 16896;
    int k = d / 264, y = d - k*264;
    int ph = (k*y) % 264;
    float ang = (float)(W0 * ph), s, c;
    sincosf(ang, &s, &c);
    tYc[d] = c; tYs[d] = s;
  }
}

// lift + zero-pad to 264x264 (fp32 in, bf16 H out; pixel pairs)
__global__ __launch_bounds__(256) void k_lift(const float* __restrict__ xin, const float* __restrict__ lw,
                                              const float* __restrict__ lb, ushort_t* __restrict__ H){
  unsigned idx = blockIdx.x*256u + threadIdx.x;       // < NIMG*HPIX exact
  unsigned p2  = idx % HPIX;
  unsigned img = idx / HPIX;
  unsigned c = img & 63u, b = img >> 6;
  unsigned x = p2 / 132u, y2 = p2 - x*132u, y = 2u*y2;
  uint_t out = 0u;
  if (x < 256 && y < 256){
    float2 xv = *(const float2*)(xin + ((size_t)(b*256+x)*256 + y));
    float wl = lw[c], bb = lb[c];
    out = pack2(wl*xv.x + bb, wl*xv.y + bb);
  }
  *(uint_t*)(H + (size_t)img*NPIX + x*PH + y) = out;
}

// fwd DFT along y: tmp[row][kk] = sum_y H[row][y] * tFT[y][kk]   (row = img*264+x)
__global__ __launch_bounds__(256) void k_fwd_y(const ushort_t* __restrict__ H, const float* __restrict__ tFT,
                                               float* __restrict__ tmp){
  int row = blockIdx.x*256 + threadIdx.x;             // 1056*256 = 270336 = NIMG*264 exact
  const uint4* hp4 = (const uint4*)(H + (size_t)row*PH);
  float acc[32];
#pragma unroll
  for (int j=0;j<32;++j) acc[j]=0.f;
  for (int y8=0; y8<33; ++y8){
    uint4 hv = hp4[y8];
    uint_t uu[4] = {hv.x, hv.y, hv.z, hv.w};
#pragma unroll
    for (int q=0;q<4;++q){
      float v0 = blo(uu[q]), v1 = bhi(uu[q]);
      const float* fr = tFT + (y8*8 + 2*q)*32;        // wave-uniform address -> scalar loads
#pragma unroll
      for (int j=0;j<32;++j) acc[j] += v0*fr[j];
#pragma unroll
      for (int j=0;j<32;++j) acc[j] += v1*fr[j+32];
    }
  }
  float* op = tmp + (size_t)row*32;
#pragma unroll
  for (int j=0;j<32;++j) op[j] = acc[j];
}

// fwd DFT along x (32 kept kx rows): Xf[img][m] = sum_x tmp[img][x][ky] * e^{-i 2pi kxe x/264}
__global__ __launch_bounds__(256) void k_fwd_x(const float* __restrict__ tmp, const float* __restrict__ tCT,
                                               const float* __restrict__ tST, float* __restrict__ Xf){
  __shared__ float st[264*32];
  int t = threadIdx.x, img = blockIdx.x;
  const float* tp = tmp + (size_t)img*(264*32);
  for (int d=t; d<264*32; d+=256) st[d] = tp[d];
  __syncthreads();
  for (int m=t; m<512; m+=256){
    int kxi = m >> 4, ky = m & 15;
    float xr=0.f, xi=0.f;
    for (int x=0; x<264; ++x){
      float tr = st[x*32 + 2*ky], ti = st[x*32 + 2*ky + 1];
      float c = tCT[x*32+kxi], s = tST[x*32+kxi];
      xr += tr*c + ti*s;
      xi += ti*c - tr*s;
    }
    ((float2*)Xf)[(size_t)img*512 + m] = make_float2(xr, xi);
  }
}

// per-mode 64x64 complex channel mix: oft[b][o][m] = sum_i Xf[b][i][m]*W[i][o][m]  (W fp32)
__global__ __launch_bounds__(512) void k_mix(const float* __restrict__ Xf, const float* __restrict__ w1,
                                             const float* __restrict__ w2, float* __restrict__ oft){
  int m = threadIdx.x;                                // mode 0..511 (kxi*16+ky)
  int o = blockIdx.x;                                 // 0..63
  const float2* X = (const float2*)Xf;
  const float2* W = (const float2*)((m < 256) ? w1 : w2);
  int mm = m & 255;
  float2 acc[16];
#pragma unroll
  for (int b=0;b<16;++b) acc[b] = make_float2(0.f,0.f);
  for (int i=0;i<64;++i){
    float2 w = W[(size_t)(i*64+o)*256 + mm];
#pragma unroll
    for (int b=0;b<16;++b){
      float2 x = X[((size_t)(b*64+i)*512) + m];
      acc[b].x += x.x*w.x - x.y*w.y;
      acc[b].y += x.x*w.y + x.y*w.x;
    }
  }
  float2* O = (float2*)oft;
#pragma unroll
  for (int b=0;b<16;++b) O[((size_t)(b*64+o)*512) + m] = acc[b];
}

// GroupNorm stats from oft via Parseval (exact).  grid 64 = (b,g); 256 threads.
__global__ __launch_bounds__(256) void k_stats_spec(const float* __restrict__ oft, float2* __restrict__ stats){
  __shared__ float sq[256], s1s[256];
  int bg = blockIdx.x, t = threadIdx.x;
  int b = bg >> 2, g = bg & 3;
  const float2* O = (const float2*)oft;
  float q = 0.f, s1 = 0.f;
  // ky>=1 modes: 2*|oft|^2
  for (int c16=0; c16<16; ++c16){
    const float2* Op = O + (size_t)(b*64 + g*16 + c16)*512;
    for (int m=t; m<512; m+=256){
      if (m & 15){ float2 v = Op[m]; q += 2.f*(v.x*v.x + v.y*v.y); }
    }
  }
  // ky==0 column: Hermitian fold (numpy c2r drops Im of bin 0)
  {
    int c16 = t >> 4, j = t & 15;
    const float2* Op = O + (size_t)(b*64 + g*16 + c16)*512;
    if (j == 0){
      float2 a0 = Op[0];
      s1 = a0.x;                         // sum over space of sp = Re oft[0,0]
      q += a0.x*a0.x;
      float2 h16 = Op[16*16];            // kxi=16 <-> kx=-16, unpaired
      q += 0.5f*(h16.x*h16.x + h16.y*h16.y);
    } else {
      float2 a = Op[j*16];               // kx=+j
      float2 bb = Op[(32-j)*16];         // kx=-j
      float rr = a.x + bb.x, ii = a.y - bb.y;   // a + conj(b)
      q += 0.5f*(rr*rr + ii*ii);
    }
  }
  sq[t] = q; s1s[t] = s1; __syncthreads();
  for (int st_=128; st_>0; st_>>=1){
    if (t < st_){ sq[t] += sq[t+st_]; s1s[t] += s1s[t+st_]; }
    __syncthreads();
  }
  if (t == 0){
    const float invN = 1.0f/1115136.0f;            // 16*264*264
    float mu  = s1s[0]*invN;
    float ssq = sq[0]*(1.0f/69696.0f);             // 1/264^2
    float var = fmaxf(ssq*invN - mu*mu, 0.f);
    stats[bg] = make_float2(mu, 1.0f/sqrtf(var + 1e-5f));
  }
}

// inverse DFT along x: z[img][x][kk] = sum_kxi oft[img][kxi][ky] * e^{+i 2pi kxe x/264} (unnormalized)
__global__ __launch_bounds__(256) void k_inv_x(const float* __restrict__ oft, const float* __restrict__ tCT,
                                               const float* __restrict__ tST, float* __restrict__ z){
  __shared__ float sof[1024];
  int t = threadIdx.x, img = blockIdx.x;
  const float* op = oft + (size_t)img*1024;
  for (int d=t; d<1024; d+=256) sof[d] = op[d];
  __syncthreads();
  for (int x=t; x<264; x+=256){
    float zr[16], zi[16];
#pragma unroll
    for (int k=0;k<16;++k){ zr[k]=0.f; zi[k]=0.f; }
    for (int kxi=0; kxi<32; ++kxi){
      float c = tCT[x*32+kxi], s = tST[x*32+kxi];
#pragma unroll
      for (int ky=0; ky<16; ++ky){
        float orr = sof[(kxi*16+ky)*2], oii = sof[(kxi*16+ky)*2 + 1];
        zr[ky] += orr*c - oii*s;
        zi[ky] += oii*c + orr*s;
      }
    }
    float* zp = z + ((size_t)img*264 + x)*32;
#pragma unroll
    for (int k=0;k<16;++k){ zp[2*k] = zr[k]; zp[2*k+1] = zi[k]; }
  }
}

// Fused: inv-y DFT (on the fly from z) -> groupnorm -> + conv1x1(H) -> gelu -> H in place.
// grid dim3(545,16); 128-px tiles; LDS = 32K(hL) + 8K(wPk) + 16K(zL) = 56 KB.
__global__ __launch_bounds__(256) void k_fused2(ushort_t* __restrict__ H, const float* __restrict__ z,
                                                const float* __restrict__ cw, const float* __restrict__ cb,
                                                const float* __restrict__ gg, const float* __restrict__ gb,
                                                const float2* __restrict__ stats,
                                                const float* __restrict__ tYc, const float* __restrict__ tYs,
                                                int do_gelu){
  __shared__ __align__(16) float hL[64*128];
  __shared__ uint_t wPk[64*32];          // wPk[i*32 + q] = pack(w[2q][i], w[2q+1][i])  (bf16 pair)
  __shared__ float zL[2*64*32];          // zL[(o*2+r)*32 + kk]
  int t = threadIdx.x, b = blockIdx.y;
  int px0 = blockIdx.x*128;
  int x0 = px0/PH;
  int x1 = (x0 < 263) ? x0+1 : 263;
  for (int d=t; d<2048; d+=256){
    int i = d>>5, q = d&31, o0 = 2*q;
    wPk[d] = pack2(cw[o0*64+i], cw[(o0+1)*64+i]);
  }
  for (int d=t; d<4096; d+=256){
    int i = d>>6, u = d&63, gp = px0 + u*2;
    float v0 = 0.f, v1 = 0.f;
    if (gp < NPIX){
      uint_t hu = *(const uint_t*)(H + (size_t)(b*64+i)*NPIX + gp);
      v0 = blo(hu); v1 = bhi(hu);
    }
    hL[i*128 + u*2] = v0; hL[i*128 + u*2 + 1] = v1;
  }
  for (int d=t; d<4096; d+=256){
    int o = d>>6, rr = (d>>5)&1, j = d&31;
    int xr = rr ? x1 : x0;
    zL[d] = z[((size_t)(b*64+o)*264 + xr)*32 + j];
  }
  __syncthreads();

  int og = t >> 6, pg = t & 63;          // wave og -> o = og*16..og*16+15 (== gn group og)
  int px = px0 + pg*2;                   // pair (px, px+1), same row (px even)
  int xr_ = px / PH;
  int y_  = px - xr_*PH;
  int r_  = xr_ - x0;
  if (r_ < 0) r_ = 0; if (r_ > 1) r_ = 1;

  float c0[15], s0[15], c1[15], s1v[15];
#pragma unroll
  for (int k=1;k<16;++k){
    int yy = (y_ < 263) ? y_ : 262;      // clamp affects only invalid lanes
    c0[k-1]  = tYc[k*264+yy];   s0[k-1]  = tYs[k*264+yy];
    c1[k-1]  = tYc[k*264+yy+1]; s1v[k-1] = tYs[k*264+yy+1];
  }

  float sp0[16], sp1[16];
#pragma unroll
  for (int oi=0; oi<16; ++oi){
    const float* zp = &zL[(((og*16+oi)*2) + r_)*32];
    float a0 = 0.5f*zp[0], a1 = a0;
#pragma unroll
    for (int k=1;k<16;++k){
      float zr = zp[2*k], zi = zp[2*k+1];
      a0 += zr*c0[k-1] - zi*s0[k-1];
      a1 += zr*c1[k-1] - zi*s1v[k-1];
    }
    sp0[oi] = a0; sp1[oi] = a1;
  }

  float2 acc[16];
#pragma unroll
  for (int oi=0;oi<16;++oi) acc[oi] = make_float2(0.f,0.f);
  for (int i=0;i<64;++i){
    float2 hv = *(const float2*)&hL[i*128 + pg*2];
    const uint_t* wp = &wPk[i*32 + og*8];
#pragma unroll
    for (int j=0;j<8;++j){
      uint_t wu = wp[j];
      float wa = blo(wu), wb = bhi(wu);
      acc[2*j].x   += wa*hv.x; acc[2*j].y   += wa*hv.y;
      acc[2*j+1].x += wb*hv.x; acc[2*j+1].y += wb*hv.y;
    }
  }

  if (px < NPIX){
    const float nrm = 2.0f/69696.0f;
    float2 st = stats[b*4 + og];
#pragma unroll
    for (int oi=0;oi<16;++oi){
      int o = og*16 + oi;
      float g_ = gg[o], be = gb[o], c_b = cb[o];
      float r0 = (sp0[oi]*nrm - st.x)*st.y*g_ + be + acc[oi].x + c_b;
      float r1 = (sp1[oi]*nrm - st.x)*st.y*g_ + be + acc[oi].y + c_b;
      if (do_gelu){ r0 = gelu_f(r0); r1 = gelu_f(r1); }
      *(uint_t*)(H + (size_t)(b*64+o)*NPIX + px) = pack2(r0, r1);
    }
  }
}

// decoder: crop -> dec1 -> gelu -> dec2 (fp32 weights & output)
__global__ __launch_bounds__(256) void k_dec(const ushort_t* __restrict__ H, const float* __restrict__ w1,
                                             const float* __restrict__ b1, const float* __restrict__ w2,
                                             const float* __restrict__ b2, float* __restrict__ out){
  __shared__ float w1L[4096];
  __shared__ float w2L[64], b1L[64];
  int t = threadIdx.x, x = blockIdx.x, b = blockIdx.y;
  for (int d=t; d<4096; d+=256) w1L[d] = w1[d];
  if (t < 64){ w2L[t] = w2[t]; b1L[t] = b1[t]; }
  __syncthreads();
  float hv[64];
#pragma unroll
  for (int c=0;c<64;++c){
    union{uint_t u; float f;} v;
    v.u = ((uint_t)H[(size_t)(b*64+c)*NPIX + x*PH + t]) << 16;
    hv[c] = v.f;
  }
  float oacc = 0.f;
  for (int o=0;o<64;++o){
    float a = b1L[o];
#pragma unroll
    for (int c=0;c<64;++c) a += w1L[o*64+c]*hv[c];
    a = gelu_f(a);
    oacc += w2L[o]*a;
  }
  out[((size_t)b*256 + x)*256 + t] = oacc + b2[0];
}

extern "C" void kernel_launch(void* const* d_in, const int* in_sizes, int n_in,
                              void* d_out, int out_size, void* d_ws, size_t ws_size,
                              hipStream_t stream){
  const float* x    = (const float*)d_in[0];
  const float* liw  = (const float*)d_in[1];
  const float* lib  = (const float*)d_in[2];
  const float* w1   = (const float*)d_in[3];
  const float* w2   = (const float*)d_in[4];
  const float* cw   = (const float*)d_in[5];
  const float* cb   = (const float*)d_in[6];
  const float* gg   = (const float*)d_in[7];
  const float* gb   = (const float*)d_in[8];
  const float* dw1  = (const float*)d_in[9];
  const float* db1  = (const float*)d_in[10];
  const float* dw2  = (const float*)d_in[11];
  const float* db2  = (const float*)d_in[12];
  float* out = (float*)d_out;

  // ws: H 142.7MB bf16 | tmp 34.6MB f32 | Xf 4.2MB | oft 4.2MB | tables 135KB | stats 512B  ~= 186 MB
  char* p = (char*)d_ws;
  ushort_t* H = (ushort_t*)p; p += (size_t)NIMG*NPIX*2;
  float* tmp  = (float*)p; p += (size_t)NIMG*264*32*4;
  float* Xf   = (float*)p; p += (size_t)NIMG*512*2*4;
  float* oft  = (float*)p; p += (size_t)NIMG*512*2*4;
  float* tFT  = (float*)p; p += 8448*4;
  float* tCT  = (float*)p; p += 8448*4;
  float* tST  = (float*)p; p += 8448*4;
  float* tYc  = (float*)p; p += 4224*4;
  float* tYs  = (float*)p; p += 4224*4;
  float2* stats = (float2*)p; p += 64*8;

  k_tables<<<132, 256, 0, stream>>>(tFT, tCT, tST, tYc, tYs);
  k_lift<<<139392, 256, 0, stream>>>(x, liw, lib, H);

  for (int k=0;k<NLAY;++k){
    k_fwd_y<<<1056, 256, 0, stream>>>(H, tFT, tmp);
    k_fwd_x<<<1024, 256, 0, stream>>>(tmp, tCT, tST, Xf);
    k_mix<<<64, 512, 0, stream>>>(Xf, w1 + (size_t)k*2097152, w2 + (size_t)k*2097152, oft);
    k_stats_spec<<<64, 256, 0, stream>>>(oft, stats);
    k_inv_x<<<1024, 256, 0, stream>>>(oft, tCT, tST, tmp);
    k_fused2<<<dim3(545,16), 256, 0, stream>>>(H, tmp, cw + (size_t)k*4096, cb + (size_t)k*64,
                                               gg + (size_t)k*64, gb + (size_t)k*64, stats, tYc, tYs, (k<3)?1:0);
  }
  k_dec<<<dim3(256,16), 256, 0, stream>>>(H, dw1, db1, dw2, db2, out);
}

// Round 5
// 2731.350 us; speedup vs baseline: 2.4710x; 2.4710x over previous
//
#include <hip/hip_runtime.h>
#include <hip/hip_bf16.h>
#include <math.h>

#define PH   264
#define NPIX (PH*PH)          // 69696
#define HPIX (NPIX/2)         // 34848 pixel pairs per image
#define NBAT 16
#define NIMG (NBAT*64)        // 1024
#define NLAY 4

typedef unsigned short ushort_t;
typedef unsigned int   uint_t;

// bf16 helpers for the INTERNAL H buffer only (all external I/O is fp32)
__device__ __forceinline__ float blo(uint_t u){ union{uint_t u; float f;} v; v.u = u << 16;        return v.f; }
__device__ __forceinline__ float bhi(uint_t u){ union{uint_t u; float f;} v; v.u = u & 0xffff0000u; return v.f; }
__device__ __forceinline__ ushort_t f2b(float f){
  __hip_bfloat16 h = __float2bfloat16(f);
  union{__hip_bfloat16 h; ushort_t s;} v; v.h = h; return v.s;
}
__device__ __forceinline__ uint_t pack2(float a, float b){
  return (uint_t)f2b(a) | ((uint_t)f2b(b) << 16);
}
__device__ __forceinline__ float gelu_f(float v){
  return v*0.5f*(1.0f + erff(v*0.70710678118654752f));
}

// DFT twiddle tables (fp32, exact integer-mod phase)
__global__ __launch_bounds__(256) void k_tables(float* __restrict__ tFT, float* __restrict__ tCT,
                                                float* __restrict__ tST, float* __restrict__ tYc,
                                                float* __restrict__ tYs){
  int idx = blockIdx.x*256 + threadIdx.x;
  const double W0 = 6.283185307179586 / 264.0;
  if (idx < 8448){                       // tFT[y*32+kk]: kk=2k -> cos, 2k+1 -> -sin (e^{-i 2pi k y/264})
    int y = idx >> 5, kk = idx & 31, k = kk >> 1;
    int ph = (k*y) % 264;
    float ang = (float)(W0 * ph), s, c;
    sincosf(ang, &s, &c);
    tFT[idx] = (kk & 1) ? -s : c;
  } else if (idx < 16896){               // tCT/tST[x*32+kxi]: cos/sin(2pi kxe x/264), kxe in [-16,15]
    int d = idx - 8448;
    int x = d >> 5, kxi = d & 31;
    int kxe = (kxi < 16) ? kxi : kxi - 32;
    int ph = ((kxe*x) % 264 + 264) % 264;
    float ang = (float)(W0 * ph), s, c;
    sincosf(ang, &s, &c);
    tCT[d] = c; tST[d] = s;
  } else if (idx < 16896 + 4224){        // tYc/tYs[k*264+y]
    int d = idx - 16896;
    int k = d / 264, y = d - k*264;
    int ph = (k*y) % 264;
    float ang = (float)(W0 * ph), s, c;
    sincosf(ang, &s, &c);
    tYc[d] = c; tYs[d] = s;
  }
}

// lift + zero-pad to 264x264 (fp32 in, bf16 H out; pixel pairs)
__global__ __launch_bounds__(256) void k_lift(const float* __restrict__ xin, const float* __restrict__ lw,
                                              const float* __restrict__ lb, ushort_t* __restrict__ H){
  unsigned idx = blockIdx.x*256u + threadIdx.x;       // < NIMG*HPIX exact
  unsigned p2  = idx % HPIX;
  unsigned img = idx / HPIX;
  unsigned c = img & 63u, b = img >> 6;
  unsigned x = p2 / 132u, y2 = p2 - x*132u, y = 2u*y2;
  uint_t out = 0u;
  if (x < 256 && y < 256){
    float2 xv = *(const float2*)(xin + ((size_t)(b*256+x)*256 + y));
    float wl = lw[c], bb = lb[c];
    out = pack2(wl*xv.x + bb, wl*xv.y + bb);
  }
  *(uint_t*)(H + (size_t)img*NPIX + x*PH + y) = out;
}

// fwd DFT along y: tmp[row][kk] = sum_y H[row][y] * tFT[y][kk]   (row = img*264+x)
__global__ __launch_bounds__(256) void k_fwd_y(const ushort_t* __restrict__ H, const float* __restrict__ tFT,
                                               float* __restrict__ tmp){
  int row = blockIdx.x*256 + threadIdx.x;             // 1056*256 = 270336 = NIMG*264 exact
  const uint4* hp4 = (const uint4*)(H + (size_t)row*PH);
  float acc[32];
#pragma unroll
  for (int j=0;j<32;++j) acc[j]=0.f;
  for (int y8=0; y8<33; ++y8){
    uint4 hv = hp4[y8];
    uint_t uu[4] = {hv.x, hv.y, hv.z, hv.w};
#pragma unroll
    for (int q=0;q<4;++q){
      float v0 = blo(uu[q]), v1 = bhi(uu[q]);
      const float* fr = tFT + (y8*8 + 2*q)*32;        // wave-uniform address -> scalar loads
#pragma unroll
      for (int j=0;j<32;++j) acc[j] += v0*fr[j];
#pragma unroll
      for (int j=0;j<32;++j) acc[j] += v1*fr[j+32];
    }
  }
  float* op = tmp + (size_t)row*32;
#pragma unroll
  for (int j=0;j<32;++j) op[j] = acc[j];
}

// fwd DFT along x (32 kept kx rows): Xf[img][m] = sum_x tmp[img][x][ky] * e^{-i 2pi kxe x/264}
__global__ __launch_bounds__(256) void k_fwd_x(const float* __restrict__ tmp, const float* __restrict__ tCT,
                                               const float* __restrict__ tST, float* __restrict__ Xf){
  __shared__ float st[264*32];
  int t = threadIdx.x, img = blockIdx.x;
  const float* tp = tmp + (size_t)img*(264*32);
  for (int d=t; d<264*32; d+=256) st[d] = tp[d];
  __syncthreads();
  for (int m=t; m<512; m+=256){
    int kxi = m >> 4, ky = m & 15;
    float xr=0.f, xi=0.f;
    for (int x=0; x<264; ++x){
      float tr = st[x*32 + 2*ky], ti = st[x*32 + 2*ky + 1];
      float c = tCT[x*32+kxi], s = tST[x*32+kxi];
      xr += tr*c + ti*s;
      xi += ti*c - tr*s;
    }
    ((float2*)Xf)[(size_t)img*512 + m] = make_float2(xr, xi);
  }
}

// per-mode 64x64 complex channel mix: oft[b][o][m] = sum_i Xf[b][i][m]*W[i][o][m]
// grid (64 o, 4 bq): each block does 4 batches -> 256 blocks
__global__ __launch_bounds__(512) void k_mix(const float* __restrict__ Xf, const float* __restrict__ w1,
                                             const float* __restrict__ w2, float* __restrict__ oft){
  int m = threadIdx.x;                                // mode 0..511 (kxi*16+ky)
  int o = blockIdx.x;                                 // 0..63
  int b0 = blockIdx.y*4;
  const float2* X = (const float2*)Xf;
  const float2* W = (const float2*)((m < 256) ? w1 : w2);
  int mm = m & 255;
  float2 acc[4];
#pragma unroll
  for (int b=0;b<4;++b) acc[b] = make_float2(0.f,0.f);
  for (int i=0;i<64;++i){
    float2 w = W[(size_t)(i*64+o)*256 + mm];
#pragma unroll
    for (int b=0;b<4;++b){
      float2 x = X[((size_t)((b0+b)*64+i)*512) + m];
      acc[b].x += x.x*w.x - x.y*w.y;
      acc[b].y += x.x*w.y + x.y*w.x;
    }
  }
  float2* O = (float2*)oft;
#pragma unroll
  for (int b=0;b<4;++b) O[((size_t)((b0+b)*64+o)*512) + m] = acc[b];
}

// GroupNorm stats from oft via Parseval (exact).  grid 64 = (b,g); 256 threads.
__global__ __launch_bounds__(256) void k_stats_spec(const float* __restrict__ oft, float2* __restrict__ stats){
  __shared__ float sq[256], s1s[256];
  int bg = blockIdx.x, t = threadIdx.x;
  int b = bg >> 2, g = bg & 3;
  const float2* O = (const float2*)oft;
  float q = 0.f, s1 = 0.f;
  // ky>=1 modes: 2*|oft|^2
  for (int c16=0; c16<16; ++c16){
    const float2* Op = O + (size_t)(b*64 + g*16 + c16)*512;
    for (int m=t; m<512; m+=256){
      if (m & 15){ float2 v = Op[m]; q += 2.f*(v.x*v.x + v.y*v.y); }
    }
  }
  // ky==0 column: Hermitian fold (numpy c2r drops Im of bin 0)
  {
    int c16 = t >> 4, j = t & 15;
    const float2* Op = O + (size_t)(b*64 + g*16 + c16)*512;
    if (j == 0){
      float2 a0 = Op[0];
      s1 = a0.x;
      q += a0.x*a0.x;
      float2 h16 = Op[16*16];
      q += 0.5f*(h16.x*h16.x + h16.y*h16.y);
    } else {
      float2 a = Op[j*16];
      float2 bb = Op[(32-j)*16];
      float rr = a.x + bb.x, ii = a.y - bb.y;
      q += 0.5f*(rr*rr + ii*ii);
    }
  }
  sq[t] = q; s1s[t] = s1; __syncthreads();
  for (int st_=128; st_>0; st_>>=1){
    if (t < st_){ sq[t] += sq[t+st_]; s1s[t] += s1s[t+st_]; }
    __syncthreads();
  }
  if (t == 0){
    const float invN = 1.0f/1115136.0f;            // 16*264*264
    float mu  = s1s[0]*invN;
    float ssq = sq[0]*(1.0f/69696.0f);             // 1/264^2
    float var = fmaxf(ssq*invN - mu*mu, 0.f);
    stats[bg] = make_float2(mu, 1.0f/sqrtf(var + 1e-5f));
  }
}

// inverse DFT along x: z[img][x][kk] = sum_kxi oft[img][kxi][ky] * e^{+i 2pi kxe x/264} (unnormalized)
__global__ __launch_bounds__(256) void k_inv_x(const float* __restrict__ oft, const float* __restrict__ tCT,
                                               const float* __restrict__ tST, float* __restrict__ z){
  __shared__ float sof[1024];
  int t = threadIdx.x, img = blockIdx.x;
  const float* op = oft + (size_t)img*1024;
  for (int d=t; d<1024; d+=256) sof[d] = op[d];
  __syncthreads();
  for (int x=t; x<264; x+=256){
    float zr[16], zi[16];
#pragma unroll
    for (int k=0;k<16;++k){ zr[k]=0.f; zi[k]=0.f; }
    for (int kxi=0; kxi<32; ++kxi){
      float c = tCT[x*32+kxi], s = tST[x*32+kxi];
#pragma unroll
      for (int ky=0; ky<16; ++ky){
        float orr = sof[(kxi*16+ky)*2], oii = sof[(kxi*16+ky)*2 + 1];
        zr[ky] += orr*c - oii*s;
        zi[ky] += oii*c + orr*s;
      }
    }
    float* zp = z + ((size_t)img*264 + x)*32;
#pragma unroll
    for (int k=0;k<16;++k){ zp[2*k] = zr[k]; zp[2*k+1] = zi[k]; }
  }
}

// Fused: conv1x1(H) -> [inv-y DFT from z -> gn] -> add -> gelu -> H in place.
// grid dim3(545,16); 128-px tiles; LDS = 16K(hPk) + 8K(wPk) + 16K(zL) = 40 KB -> 3 blocks/CU.
// Register discipline: acc[16]x2 live in conv phase; twiddles (60) loaded AFTER conv -> peak ~105 VGPR.
__global__ __launch_bounds__(256, 4) void k_fused2(ushort_t* __restrict__ H, const float* __restrict__ z,
                                                const float* __restrict__ cw, const float* __restrict__ cb,
                                                const float* __restrict__ gg, const float* __restrict__ gb,
                                                const float2* __restrict__ stats,
                                                const float* __restrict__ tYc, const float* __restrict__ tYs,
                                                int do_gelu){
  __shared__ uint_t hPk[64*64];          // packed bf16 pixel-pairs: hPk[i*64+u]
  __shared__ uint_t wPk[64*32];          // wPk[i*32 + q] = pack(w[2q][i], w[2q+1][i])
  __shared__ float zL[2*64*32];          // zL[(o*2+r)*32 + kk]
  int t = threadIdx.x, b = blockIdx.y;
  int px0 = blockIdx.x*128;
  int x0 = px0/PH;
  int x1 = (x0 < 263) ? x0+1 : 263;
  for (int d=t; d<2048; d+=256){
    int i = d>>5, q = d&31, o0 = 2*q;
    wPk[d] = pack2(cw[o0*64+i], cw[(o0+1)*64+i]);
  }
  for (int d=t; d<4096; d+=256){
    int i = d>>6, u = d&63, gp = px0 + u*2;
    hPk[d] = (gp < NPIX) ? *(const uint_t*)(H + (size_t)(b*64+i)*NPIX + gp) : 0u;
  }
  for (int d=t; d<4096; d+=256){
    int o = d>>6, rr = (d>>5)&1, j = d&31;
    int xr = rr ? x1 : x0;
    zL[d] = z[((size_t)(b*64+o)*264 + xr)*32 + j];
  }
  __syncthreads();

  int og = t >> 6, pg = t & 63;          // wave og -> o = og*16..og*16+15 (== gn group og)
  int px = px0 + pg*2;                   // pair (px, px+1): same row, y even
  int xr_ = px / PH;
  int y_  = px - xr_*PH;
  int r_  = xr_ - x0;
  if (r_ < 0) r_ = 0; if (r_ > 1) r_ = 1;

  // ---- conv phase (acc live: 32 VGPR) ----
  float2 acc[16];
#pragma unroll
  for (int oi=0;oi<16;++oi) acc[oi] = make_float2(0.f,0.f);
  for (int i=0;i<64;++i){
    uint_t hu = hPk[i*64 + pg];
    float hx = blo(hu), hy = bhi(hu);
    const uint_t* wp = &wPk[i*32 + og*8];
#pragma unroll
    for (int j=0;j<8;++j){
      uint_t wu = wp[j];
      float wa = blo(wu), wb = bhi(wu);
      acc[2*j].x   += wa*hx; acc[2*j].y   += wa*hy;
      acc[2*j+1].x += wb*hx; acc[2*j+1].y += wb*hy;
    }
  }

  // ---- twiddle load (after conv; 60 VGPR live alongside acc) ----
  int yy = (y_ < 263) ? y_ : 262;        // clamp affects only invalid lanes
  float c0[15], s0[15], c1[15], s1v[15];
#pragma unroll
  for (int k=1;k<16;++k){
    c0[k-1]  = tYc[k*264+yy];   s0[k-1]  = tYs[k*264+yy];
    c1[k-1]  = tYc[k*264+yy+1]; s1v[k-1] = tYs[k*264+yy+1];
  }

  if (px < NPIX){
    const float nrm = 2.0f/69696.0f;
    float2 st = stats[b*4 + og];
#pragma unroll
    for (int oi=0;oi<16;++oi){
      int o = og*16 + oi;
      // inv-y on the fly for this channel
      const float* zp = &zL[(((o)*2) + r_)*32];
      float a0 = 0.5f*zp[0], a1 = a0;
#pragma unroll
      for (int k=1;k<16;++k){
        float zr = zp[2*k], zi = zp[2*k+1];
        a0 += zr*c0[k-1] - zi*s0[k-1];
        a1 += zr*c1[k-1] - zi*s1v[k-1];
      }
      float g_ = gg[o], be = gb[o], c_b = cb[o];
      float r0 = (a0*nrm - st.x)*st.y*g_ + be + acc[oi].x + c_b;
      float r1 = (a1*nrm - st.x)*st.y*g_ + be + acc[oi].y + c_b;
      if (do_gelu){ r0 = gelu_f(r0); r1 = gelu_f(r1); }
      *(uint_t*)(H + (size_t)(b*64+o)*NPIX + px) = pack2(r0, r1);
    }
  }
}

// decoder: crop -> dec1 -> gelu -> dec2 (fp32 weights & output)
__global__ __launch_bounds__(256) void k_dec(const ushort_t* __restrict__ H, const float* __restrict__ w1,
                                             const float* __restrict__ b1, const float* __restrict__ w2,
                                             const float* __restrict__ b2, float* __restrict__ out){
  __shared__ float w1L[4096];
  __shared__ float w2L[64], b1L[64];
  int t = threadIdx.x, x = blockIdx.x, b = blockIdx.y;
  for (int d=t; d<4096; d+=256) w1L[d] = w1[d];
  if (t < 64){ w2L[t] = w2[t]; b1L[t] = b1[t]; }
  __syncthreads();
  float hv[64];
#pragma unroll
  for (int c=0;c<64;++c){
    union{uint_t u; float f;} v;
    v.u = ((uint_t)H[(size_t)(b*64+c)*NPIX + x*PH + t]) << 16;
    hv[c] = v.f;
  }
  float oacc = 0.f;
  for (int o=0;o<64;++o){
    float a = b1L[o];
#pragma unroll
    for (int c=0;c<64;++c) a += w1L[o*64+c]*hv[c];
    a = gelu_f(a);
    oacc += w2L[o]*a;
  }
  out[((size_t)b*256 + x)*256 + t] = oacc + b2[0];
}

extern "C" void kernel_launch(void* const* d_in, const int* in_sizes, int n_in,
                              void* d_out, int out_size, void* d_ws, size_t ws_size,
                              hipStream_t stream){
  const float* x    = (const float*)d_in[0];
  const float* liw  = (const float*)d_in[1];
  const float* lib  = (const float*)d_in[2];
  const float* w1   = (const float*)d_in[3];
  const float* w2   = (const float*)d_in[4];
  const float* cw   = (const float*)d_in[5];
  const float* cb   = (const float*)d_in[6];
  const float* gg   = (const float*)d_in[7];
  const float* gb   = (const float*)d_in[8];
  const float* dw1  = (const float*)d_in[9];
  const float* db1  = (const float*)d_in[10];
  const float* dw2  = (const float*)d_in[11];
  const float* db2  = (const float*)d_in[12];
  float* out = (float*)d_out;

  // ws: H 142.7MB bf16 | tmp 34.6MB f32 | Xf 4.2MB | oft 4.2MB | tables 135KB | stats 512B  ~= 186 MB
  char* p = (char*)d_ws;
  ushort_t* H = (ushort_t*)p; p += (size_t)NIMG*NPIX*2;
  float* tmp  = (float*)p; p += (size_t)NIMG*264*32*4;
  float* Xf   = (float*)p; p += (size_t)NIMG*512*2*4;
  float* oft  = (float*)p; p += (size_t)NIMG*512*2*4;
  float* tFT  = (float*)p; p += 8448*4;
  float* tCT  = (float*)p; p += 8448*4;
  float* tST  = (float*)p; p += 8448*4;
  float* tYc  = (float*)p; p += 4224*4;
  float* tYs  = (float*)p; p += 4224*4;
  float2* stats = (float2*)p; p += 64*8;

  k_tables<<<132, 256, 0, stream>>>(tFT, tCT, tST, tYc, tYs);
  k_lift<<<139392, 256, 0, stream>>>(x, liw, lib, H);

  for (int k=0;k<NLAY;++k){
    k_fwd_y<<<1056, 256, 0, stream>>>(H, tFT, tmp);
    k_fwd_x<<<1024, 256, 0, stream>>>(tmp, tCT, tST, Xf);
    k_mix<<<dim3(64,4), 512, 0, stream>>>(Xf, w1 + (size_t)k*2097152, w2 + (size_t)k*2097152, oft);
    k_stats_spec<<<64, 256, 0, stream>>>(oft, stats);
    k_inv_x<<<1024, 256, 0, stream>>>(oft, tCT, tST, tmp);
    k_fused2<<<dim3(545,16), 256, 0, stream>>>(H, tmp, cw + (size_t)k*4096, cb + (size_t)k*64,
                                               gg + (size_t)k*64, gb + (size_t)k*64, stats, tYc, tYs, (k<3)?1:0);
  }
  k_dec<<<dim3(256,16), 256, 0, stream>>>(H, dw1, db1, dw2, db2, out);
}

// Round 6
// 2412.732 us; speedup vs baseline: 2.7973x; 1.1321x over previous
//
#include <hip/hip_runtime.h>
#include <hip/hip_bf16.h>
#include <math.h>

#define PH   264
#define NPIX (PH*PH)          // 69696
#define NBAT 16
#define NIMG (NBAT*64)        // 1024
#define NLAY 4
#define TILE 144              // px per block in k_fused2; 69696 = 484*144; 144 = 9*16
#define NMT  9

typedef unsigned short ushort_t;
typedef unsigned int   uint_t;
typedef __attribute__((ext_vector_type(8))) short short8;   // 8 bf16 = 4 VGPR (MFMA A/B frag)
typedef __attribute__((ext_vector_type(4))) float float4v;  // MFMA C/D frag

__device__ __forceinline__ float blo(uint_t u){ union{uint_t u; float f;} v; v.u = u << 16;        return v.f; }
__device__ __forceinline__ float bhi(uint_t u){ union{uint_t u; float f;} v; v.u = u & 0xffff0000u; return v.f; }
__device__ __forceinline__ float b2f(ushort_t s){ union{uint_t u; float f;} v; v.u = ((uint_t)s) << 16; return v.f; }
__device__ __forceinline__ ushort_t f2b(float f){
  __hip_bfloat16 h = __float2bfloat16(f);
  union{__hip_bfloat16 h; ushort_t s;} v; v.h = h; return v.s;
}
__device__ __forceinline__ float gelu_f(float v){
  return v*0.5f*(1.0f + erff(v*0.70710678118654752f));
}

// DFT twiddle tables (fp32, exact integer-mod phase)
__global__ __launch_bounds__(256) void k_tables(float* __restrict__ tFT, float* __restrict__ tCT,
                                                float* __restrict__ tST, float* __restrict__ tYc,
                                                float* __restrict__ tYs){
  int idx = blockIdx.x*256 + threadIdx.x;
  const double W0 = 6.283185307179586 / 264.0;
  if (idx < 8448){                       // tFT[y*32+kk]: kk=2k -> cos, 2k+1 -> -sin (e^{-i 2pi k y/264})
    int y = idx >> 5, kk = idx & 31, k = kk >> 1;
    int ph = (k*y) % 264;
    float ang = (float)(W0 * ph), s, c;
    sincosf(ang, &s, &c);
    tFT[idx] = (kk & 1) ? -s : c;
  } else if (idx < 16896){               // tCT/tST[x*32+kxi]: cos/sin(2pi kxe x/264), kxe in [-16,15]
    int d = idx - 8448;
    int x = d >> 5, kxi = d & 31;
    int kxe = (kxi < 16) ? kxi : kxi - 32;
    int ph = ((kxe*x) % 264 + 264) % 264;
    float ang = (float)(W0 * ph), s, c;
    sincosf(ang, &s, &c);
    tCT[d] = c; tST[d] = s;
  } else if (idx < 16896 + 4224){        // tYc/tYs[k*264+y]
    int d = idx - 16896;
    int k = d / 264, y = d - k*264;
    int ph = (k*y) % 264;
    float ang = (float)(W0 * ph), s, c;
    sincosf(ang, &s, &c);
    tYc[d] = c; tYs[d] = s;
  }
}

// lift + zero-pad; H pixel-major [b][px][c] bf16
__global__ __launch_bounds__(256) void k_lift(const float* __restrict__ xin, const float* __restrict__ lw,
                                              const float* __restrict__ lb, ushort_t* __restrict__ H){
  int t = threadIdx.x, b = blockIdx.y;
  int px = blockIdx.x*4 + (t>>6);
  int c  = t & 63;
  int x = px / PH, y = px - x*PH;
  float v = 0.f;
  if (x < 256 && y < 256) v = lw[c]*xin[((size_t)(b*256+x))*256 + y] + lb[c];
  H[((size_t)b*NPIX + px)*64 + c] = f2b(v);
}

// fwd DFT along y: tmp[b][x][kk][c] = sum_y H[b][x*264+y][c] * tFT[y][kk]
// thread = (b,x,c); 4 rows/block; twiddles wave-uniform -> s_loads
__global__ __launch_bounds__(256) void k_fwd_y(const ushort_t* __restrict__ H, const float* __restrict__ tFT,
                                               float* __restrict__ tmp){
  int t = threadIdx.x;
  int row = blockIdx.x*4 + (t>>6);        // 0..4223 = b*264+x
  int c = t & 63;
  int b = row / 264, x = row - b*264;
  const ushort_t* hp = H + ((size_t)b*NPIX + (size_t)x*PH)*64 + c;
  float acc[32];
#pragma unroll
  for (int j=0;j<32;++j) acc[j]=0.f;
  for (int y=0; y<PH; ++y){
    float h = b2f(hp[(size_t)y*64]);
    const float* fr = tFT + y*32;         // wave-uniform
#pragma unroll
    for (int j=0;j<32;++j) acc[j] += h*fr[j];
  }
  float* op = tmp + (((size_t)row)*32)*64 + c;
#pragma unroll
  for (int j=0;j<32;++j) op[(size_t)j*64] = acc[j];
}

// fwd DFT along x: Xf[img=(b*64+c)][m] = sum_x tmp[b][x][ky-pair][c] * e^{-i..}
// block = (mgrp, b): 4 m per block, lanes = c (coalesced); twiddles wave-uniform
__global__ __launch_bounds__(256) void k_fwd_x(const float* __restrict__ tmp, const float* __restrict__ tCT,
                                               const float* __restrict__ tST, float* __restrict__ Xf){
  int t = threadIdx.x, b = blockIdx.y;
  int m = blockIdx.x*4 + (t>>6);          // 0..511
  int c = t & 63;
  int kxi = m >> 4, ky = m & 15;
  float xr=0.f, xi=0.f;
  const float* base = tmp + ((size_t)b*264*32 + 2*ky)*64 + c;
  for (int x=0; x<PH; ++x){
    float tr = base[(size_t)x*32*64];
    float ti = base[(size_t)x*32*64 + 64];
    float cc = tCT[x*32+kxi], ss = tST[x*32+kxi];   // wave-uniform
    xr += tr*cc + ti*ss;
    xi += ti*cc - tr*ss;
  }
  ((float2*)Xf)[(size_t)(b*64+c)*512 + m] = make_float2(xr, xi);
}

// per-mode 64x64 complex channel mix (unchanged)
__global__ __launch_bounds__(512) void k_mix(const float* __restrict__ Xf, const float* __restrict__ w1,
                                             const float* __restrict__ w2, float* __restrict__ oft){
  int m = threadIdx.x;
  int o = blockIdx.x;
  int b0 = blockIdx.y*4;
  const float2* X = (const float2*)Xf;
  const float2* W = (const float2*)((m < 256) ? w1 : w2);
  int mm = m & 255;
  float2 acc[4];
#pragma unroll
  for (int b=0;b<4;++b) acc[b] = make_float2(0.f,0.f);
  for (int i=0;i<64;++i){
    float2 w = W[(size_t)(i*64+o)*256 + mm];
#pragma unroll
    for (int b=0;b<4;++b){
      float2 x = X[((size_t)((b0+b)*64+i)*512) + m];
      acc[b].x += x.x*w.x - x.y*w.y;
      acc[b].y += x.x*w.y + x.y*w.x;
    }
  }
  float2* O = (float2*)oft;
#pragma unroll
  for (int b=0;b<4;++b) O[((size_t)((b0+b)*64+o)*512) + m] = acc[b];
}

// GroupNorm stats from oft via Parseval (unchanged)
__global__ __launch_bounds__(256) void k_stats_spec(const float* __restrict__ oft, float2* __restrict__ stats){
  __shared__ float sq[256], s1s[256];
  int bg = blockIdx.x, t = threadIdx.x;
  int b = bg >> 2, g = bg & 3;
  const float2* O = (const float2*)oft;
  float q = 0.f, s1 = 0.f;
  for (int c16=0; c16<16; ++c16){
    const float2* Op = O + (size_t)(b*64 + g*16 + c16)*512;
    for (int m=t; m<512; m+=256){
      if (m & 15){ float2 v = Op[m]; q += 2.f*(v.x*v.x + v.y*v.y); }
    }
  }
  {
    int c16 = t >> 4, j = t & 15;
    const float2* Op = O + (size_t)(b*64 + g*16 + c16)*512;
    if (j == 0){
      float2 a0 = Op[0];
      s1 = a0.x;
      q += a0.x*a0.x;
      float2 h16 = Op[16*16];
      q += 0.5f*(h16.x*h16.x + h16.y*h16.y);
    } else {
      float2 a = Op[j*16];
      float2 bb = Op[(32-j)*16];
      float rr = a.x + bb.x, ii = a.y - bb.y;
      q += 0.5f*(rr*rr + ii*ii);
    }
  }
  sq[t] = q; s1s[t] = s1; __syncthreads();
  for (int st_=128; st_>0; st_>>=1){
    if (t < st_){ sq[t] += sq[t+st_]; s1s[t] += s1s[t+st_]; }
    __syncthreads();
  }
  if (t == 0){
    const float invN = 1.0f/1115136.0f;
    float mu  = s1s[0]*invN;
    float ssq = sq[0]*(1.0f/69696.0f);
    float var = fmaxf(ssq*invN - mu*mu, 0.f);
    stats[bg] = make_float2(mu, 1.0f/sqrtf(var + 1e-5f));
  }
}

// inverse DFT along x (unchanged): z[img=(b*64+c)][x][kk]
__global__ __launch_bounds__(256) void k_inv_x(const float* __restrict__ oft, const float* __restrict__ tCT,
                                               const float* __restrict__ tST, float* __restrict__ z){
  __shared__ float sof[1024];
  int t = threadIdx.x, img = blockIdx.x;
  const float* op = oft + (size_t)img*1024;
  for (int d=t; d<1024; d+=256) sof[d] = op[d];
  __syncthreads();
  for (int x=t; x<264; x+=256){
    float zr[16], zi[16];
#pragma unroll
    for (int k=0;k<16;++k){ zr[k]=0.f; zi[k]=0.f; }
    for (int kxi=0; kxi<32; ++kxi){
      float c = tCT[x*32+kxi], s = tST[x*32+kxi];
#pragma unroll
      for (int ky=0; ky<16; ++ky){
        float orr = sof[(kxi*16+ky)*2], oii = sof[(kxi*16+ky)*2 + 1];
        zr[ky] += orr*c - oii*s;
        zi[ky] += oii*c + orr*s;
      }
    }
    float* zp = z + ((size_t)img*264 + x)*32;
#pragma unroll
    for (int k=0;k<16;++k){ zp[2*k] = zr[k]; zp[2*k+1] = zi[k]; }
  }
}

// Fully-MFMA fused layer: H(new) = gelu( TW·(z·alpha) + H·Wconv + beta ), in place on H.
// C tile [px][o]; A(conv)=H[px][i] direct from global; B(conv)=cw[o][i] from global->bf16.
// sp-part: A=TW (twiddle hi+lo bf16), B=z*alpha (hi+lo bf16), 3 cross-term MFMAs.
// grid (484,16), 256 thr (4 waves); wave w owns m-tiles {w, w+4, w+8}.
__global__ __launch_bounds__(256, 3) void k_fused2(ushort_t* __restrict__ H, const float* __restrict__ z,
                                                const float* __restrict__ cw, const float* __restrict__ cb,
                                                const float* __restrict__ gg, const float* __restrict__ gb,
                                                const float2* __restrict__ stats,
                                                const float* __restrict__ tYc, const float* __restrict__ tYs,
                                                int do_gelu){
  __shared__ short TWhi[TILE*40];        // [px_local][kk] stride 40 (2-way bank, 16B aligned)
  __shared__ short TWlo[TILE*40];
  __shared__ short TWm[4][16*40];        // masked twiddles for the row-mixed m-tile: [r*2+p]
  __shared__ short zBT[4][64*40];        // (z*alpha)^T [o][kk], [r*2+p] (r=row, p=hi/lo)
  int t = threadIdx.x, b = blockIdx.y;
  int px0 = blockIdx.x*TILE;
  int x0 = px0 / PH;
  int pxb = (x0+1)*PH - px0;                       // local index of first px of next row
  int x1 = (x0 < PH-1) ? x0+1 : PH-1;
  int mtmix = (pxb < TILE && (pxb & 15)) ? (pxb >> 4) : -1;

  // build zBT = z * alpha (alpha = rstd*g*nrm), hi/lo
  for (int d=t; d<2048; d+=256){
    int o = d>>5, k = d&31;
    float al = stats[b*4 + (o>>4)].y * gg[o] * (2.0f/69696.0f);
    int xr2[2] = {x0, x1};
#pragma unroll
    for (int r=0;r<2;++r){
      float v = z[((size_t)(b*64+o)*PH + xr2[r])*32 + k] * al;
      ushort_t hi = f2b(v);
      zBT[r*2+0][o*40+k] = (short)hi;
      zBT[r*2+1][o*40+k] = (short)f2b(v - b2f(hi));
    }
  }
  // build TW (per-px twiddle row for its own y), hi/lo
  for (int d=t; d<TILE*32; d+=256){
    int px = d>>5, kk = d&31;
    int gpx = px0 + px;
    int x = gpx / PH, y = gpx - x*PH;
    int j = kk >> 1;
    float v;
    if (kk == 0) v = 0.5f;
    else if (kk == 1) v = 0.f;
    else v = (kk & 1) ? -tYs[j*PH+y] : tYc[j*PH+y];
    ushort_t hi = f2b(v);
    TWhi[px*40+kk] = (short)hi;
    TWlo[px*40+kk] = (short)f2b(v - b2f(hi));
  }
  // masked twiddles for mixed tile
  if (mtmix >= 0){
    for (int d=t; d<512; d+=256){
      int pl = d>>5, kk = d&31;
      int gpx = px0 + mtmix*16 + pl;
      int x = gpx / PH, y = gpx - x*PH;
      int j = kk >> 1;
      float v;
      if (kk == 0) v = 0.5f;
      else if (kk == 1) v = 0.f;
      else v = (kk & 1) ? -tYs[j*PH+y] : tYc[j*PH+y];
      int r = x - x0;
      float v0 = (r==0) ? v : 0.f;
      float v1 = (r==1) ? v : 0.f;
      ushort_t h0 = f2b(v0), h1 = f2b(v1);
      TWm[0][pl*40+kk] = (short)h0; TWm[1][pl*40+kk] = (short)f2b(v0 - b2f(h0));
      TWm[2][pl*40+kk] = (short)h1; TWm[3][pl*40+kk] = (short)f2b(v1 - b2f(h1));
    }
  }
  __syncthreads();

  int w = t >> 6, lane = t & 63;
  int quad = lane >> 4, lcol = lane & 15;

  // conv B frags (weights, L2-hot): B[k=i][n=o], lane n=lcol, k=quad*8+j
  short8 Bc[4][2];
#pragma unroll
  for (int n=0;n<4;++n){
#pragma unroll
    for (int s=0;s<2;++s){
      const float* wp = cw + (size_t)(n*16+lcol)*64 + s*32 + quad*8;
      short8 bb;
#pragma unroll
      for (int j=0;j<8;++j) bb[j] = (short)f2b(wp[j]);
      Bc[n][s] = bb;
    }
  }

  float4v acc[3][4];
#pragma unroll
  for (int si=0;si<3;++si)
#pragma unroll
    for (int n=0;n<4;++n) acc[si][n] = (float4v){0.f,0.f,0.f,0.f};

#pragma unroll
  for (int si=0;si<3;++si){
    int mt = w + 4*si;
    if (mt >= NMT) continue;
    int pxr = px0 + mt*16 + lcol;                  // A row (px) for this lane
    const ushort_t* hp = H + ((size_t)b*NPIX + pxr)*64 + quad*8;
    union{uint4 u; short8 s;} a0, a1;
    a0.u = *(const uint4*)hp;
    a1.u = *(const uint4*)(hp + 32);
    int twr = (mt*16 + lcol)*40 + quad*8;
    short8 Ath = *(const short8*)&TWhi[twr];
    short8 Atl = *(const short8*)&TWlo[twr];
    int rr = (mt*16 >= pxb) ? 1 : 0;
#pragma unroll
    for (int n=0;n<4;++n){
      float4v a = acc[si][n];
      a = __builtin_amdgcn_mfma_f32_16x16x32_bf16(a0.s, Bc[n][0], a, 0, 0, 0);
      a = __builtin_amdgcn_mfma_f32_16x16x32_bf16(a1.s, Bc[n][1], a, 0, 0, 0);
      int ob = (n*16+lcol)*40 + quad*8;
      if (mt != mtmix){
        short8 Bzh = *(const short8*)&zBT[rr*2+0][ob];
        short8 Bzl = *(const short8*)&zBT[rr*2+1][ob];
        a = __builtin_amdgcn_mfma_f32_16x16x32_bf16(Ath, Bzh, a, 0, 0, 0);
        a = __builtin_amdgcn_mfma_f32_16x16x32_bf16(Ath, Bzl, a, 0, 0, 0);
        a = __builtin_amdgcn_mfma_f32_16x16x32_bf16(Atl, Bzh, a, 0, 0, 0);
      } else {
#pragma unroll
        for (int r=0;r<2;++r){
          short8 Amh = *(const short8*)&TWm[r*2+0][lcol*40 + quad*8];
          short8 Aml = *(const short8*)&TWm[r*2+1][lcol*40 + quad*8];
          short8 Bzh = *(const short8*)&zBT[r*2+0][ob];
          short8 Bzl = *(const short8*)&zBT[r*2+1][ob];
          a = __builtin_amdgcn_mfma_f32_16x16x32_bf16(Amh, Bzh, a, 0, 0, 0);
          a = __builtin_amdgcn_mfma_f32_16x16x32_bf16(Amh, Bzl, a, 0, 0, 0);
          a = __builtin_amdgcn_mfma_f32_16x16x32_bf16(Aml, Bzh, a, 0, 0, 0);
        }
      }
      acc[si][n] = a;
    }
  }

  // epilogue: + (gb - mu*rstd*g + cb), gelu, store bf16
#pragma unroll
  for (int si=0;si<3;++si){
    int mt = w + 4*si;
    if (mt >= NMT) continue;
#pragma unroll
    for (int n=0;n<4;++n){
      int o = n*16 + lcol;
      float2 st = stats[b*4 + n];
      float beta = gb[o] - st.x*st.y*gg[o] + cb[o];
#pragma unroll
      for (int reg=0; reg<4; ++reg){
        int px = px0 + mt*16 + quad*4 + reg;
        float v = acc[si][n][reg] + beta;
        if (do_gelu) v = gelu_f(v);
        H[((size_t)b*NPIX + px)*64 + o] = f2b(v);
      }
    }
  }
}

// decoder: crop -> dec1 -> gelu -> dec2 (pixel-major H read)
__global__ __launch_bounds__(256) void k_dec(const ushort_t* __restrict__ H, const float* __restrict__ w1,
                                             const float* __restrict__ b1, const float* __restrict__ w2,
                                             const float* __restrict__ b2, float* __restrict__ out){
  __shared__ float w1L[4096];
  __shared__ float w2L[64], b1L[64];
  int t = threadIdx.x, x = blockIdx.x, b = blockIdx.y;
  for (int d=t; d<4096; d+=256) w1L[d] = w1[d];
  if (t < 64){ w2L[t] = w2[t]; b1L[t] = b1[t]; }
  __syncthreads();
  const ushort_t* hp = H + ((size_t)b*NPIX + (size_t)x*PH + t)*64;
  float hv[64];
#pragma unroll
  for (int q=0;q<8;++q){
    uint4 u = *(const uint4*)(hp + q*8);
    hv[q*8+0] = blo(u.x); hv[q*8+1] = bhi(u.x);
    hv[q*8+2] = blo(u.y); hv[q*8+3] = bhi(u.y);
    hv[q*8+4] = blo(u.z); hv[q*8+5] = bhi(u.z);
    hv[q*8+6] = blo(u.w); hv[q*8+7] = bhi(u.w);
  }
  float oacc = 0.f;
  for (int o=0;o<64;++o){
    float a = b1L[o];
#pragma unroll
    for (int c=0;c<64;++c) a += w1L[o*64+c]*hv[c];
    a = gelu_f(a);
    oacc += w2L[o]*a;
  }
  out[((size_t)b*256 + x)*256 + t] = oacc + b2[0];
}

extern "C" void kernel_launch(void* const* d_in, const int* in_sizes, int n_in,
                              void* d_out, int out_size, void* d_ws, size_t ws_size,
                              hipStream_t stream){
  const float* x    = (const float*)d_in[0];
  const float* liw  = (const float*)d_in[1];
  const float* lib  = (const float*)d_in[2];
  const float* w1   = (const float*)d_in[3];
  const float* w2   = (const float*)d_in[4];
  const float* cw   = (const float*)d_in[5];
  const float* cb   = (const float*)d_in[6];
  const float* gg   = (const float*)d_in[7];
  const float* gb   = (const float*)d_in[8];
  const float* dw1  = (const float*)d_in[9];
  const float* db1  = (const float*)d_in[10];
  const float* dw2  = (const float*)d_in[11];
  const float* db2  = (const float*)d_in[12];
  float* out = (float*)d_out;

  // ws: H 142.7MB bf16 (pixel-major) | tmp 34.6MB f32 | Xf 4.2MB | oft 4.2MB | tables | stats  ~= 186 MB
  char* p = (char*)d_ws;
  ushort_t* H = (ushort_t*)p; p += (size_t)NBAT*NPIX*64*2;
  float* tmp  = (float*)p; p += (size_t)NBAT*264*32*64*4;
  float* Xf   = (float*)p; p += (size_t)NIMG*512*2*4;
  float* oft  = (float*)p; p += (size_t)NIMG*512*2*4;
  float* tFT  = (float*)p; p += 8448*4;
  float* tCT  = (float*)p; p += 8448*4;
  float* tST  = (float*)p; p += 8448*4;
  float* tYc  = (float*)p; p += 4224*4;
  float* tYs  = (float*)p; p += 4224*4;
  float2* stats = (float2*)p; p += 64*8;

  k_tables<<<132, 256, 0, stream>>>(tFT, tCT, tST, tYc, tYs);
  k_lift<<<dim3(NPIX/4, 16), 256, 0, stream>>>(x, liw, lib, H);

  for (int k=0;k<NLAY;++k){
    k_fwd_y<<<1056, 256, 0, stream>>>(H, tFT, tmp);
    k_fwd_x<<<dim3(128,16), 256, 0, stream>>>(tmp, tCT, tST, Xf);
    k_mix<<<dim3(64,4), 512, 0, stream>>>(Xf, w1 + (size_t)k*2097152, w2 + (size_t)k*2097152, oft);
    k_stats_spec<<<64, 256, 0, stream>>>(oft, stats);
    k_inv_x<<<1024, 256, 0, stream>>>(oft, tCT, tST, tmp);
    k_fused2<<<dim3(NPIX/TILE,16), 256, 0, stream>>>(H, tmp, cw + (size_t)k*4096, cb + (size_t)k*64,
                                               gg + (size_t)k*64, gb + (size_t)k*64, stats, tYc, tYs, (k<3)?1:0);
  }
  k_dec<<<dim3(256,16), 256, 0, stream>>>(H, dw1, db1, dw2, db2, out);
}

// Round 7
// 1897.011 us; speedup vs baseline: 3.5577x; 1.2719x over previous
//
#include <hip/hip_runtime.h>
#include <hip/hip_bf16.h>
#include <math.h>

#define PH   264
#define NPIX (PH*PH)          // 69696
#define NBAT 16
#define NIMG (NBAT*64)        // 1024
#define NLAY 4

typedef unsigned short ushort_t;
typedef unsigned int   uint_t;
typedef __attribute__((ext_vector_type(8))) short short8;   // 8 bf16 = 4 VGPR (MFMA A/B frag)
typedef __attribute__((ext_vector_type(4))) float float4v;  // MFMA C/D frag

__device__ __forceinline__ float blo(uint_t u){ union{uint_t u; float f;} v; v.u = u << 16;        return v.f; }
__device__ __forceinline__ float bhi(uint_t u){ union{uint_t u; float f;} v; v.u = u & 0xffff0000u; return v.f; }
__device__ __forceinline__ float b2f(ushort_t s){ union{uint_t u; float f;} v; v.u = ((uint_t)s) << 16; return v.f; }
__device__ __forceinline__ ushort_t f2b(float f){
  __hip_bfloat16 h = __float2bfloat16(f);
  union{__hip_bfloat16 h; ushort_t s;} v; v.h = h; return v.s;
}
// fast erf (A&S 7.1.26, |err|<1.5e-7) -> exact-enough gelu at ~half the VALU of libm erff
__device__ __forceinline__ float gelu_f(float v){
  float x  = v*0.70710678118654752f;
  float ax = fabsf(x);
  float t  = 1.0f/(1.0f + 0.3275911f*ax);
  float poly = t*(0.254829592f + t*(-0.284496736f + t*(1.421413741f + t*(-1.453152027f + t*1.061405429f))));
  float er = 1.0f - poly*__expf(-ax*ax);
  er = (x < 0.f) ? -er : er;
  return 0.5f*v*(1.0f + er);
}

// DFT twiddle tables (fp32, exact integer-mod phase) + bf16 hi/lo inv-y twiddle matrix TWg[272][32]
__global__ __launch_bounds__(256) void k_tables(float* __restrict__ tFT, float* __restrict__ tCT,
                                                float* __restrict__ tST, float* __restrict__ tYc,
                                                float* __restrict__ tYs,
                                                ushort_t* __restrict__ TWh, ushort_t* __restrict__ TWl){
  int idx = blockIdx.x*256 + threadIdx.x;
  const double W0 = 6.283185307179586 / 264.0;
  if (idx < 8448){                       // tFT[y*32+kk]: kk=2k -> cos, 2k+1 -> -sin (e^{-i 2pi k y/264})
    int y = idx >> 5, kk = idx & 31, k = kk >> 1;
    int ph = (k*y) % 264;
    float ang = (float)(W0 * ph), s, c;
    sincosf(ang, &s, &c);
    tFT[idx] = (kk & 1) ? -s : c;
  } else if (idx < 16896){               // tCT/tST[x*32+kxi]: cos/sin(2pi kxe x/264), kxe in [-16,15]
    int d = idx - 8448;
    int x = d >> 5, kxi = d & 31;
    int kxe = (kxi < 16) ? kxi : kxi - 32;
    int ph = ((kxe*x) % 264 + 264) % 264;
    float ang = (float)(W0 * ph), s, c;
    sincosf(ang, &s, &c);
    tCT[d] = c; tST[d] = s;
  } else if (idx < 16896 + 4224){        // tYc/tYs[k*264+y]
    int d = idx - 16896;
    int k = d / 264, y = d - k*264;
    int ph = (k*y) % 264;
    float ang = (float)(W0 * ph), s, c;
    sincosf(ang, &s, &c);
    tYc[d] = c; tYs[d] = s;
  } else if (idx < 21120 + 8704){        // TWg[y][kk]: inv-y row; rows >=264 zero (padding m-tile)
    int d = idx - 21120;
    int y = d >> 5, kk = d & 31;
    float v = 0.f;
    if (y < 264){
      if (kk == 0) v = 0.5f;
      else if (kk > 1){
        int j = kk >> 1;
        int ph = (j*y) % 264;
        float ang = (float)(W0 * ph), s, c;
        sincosf(ang, &s, &c);
        v = (kk & 1) ? -s : c;
      }
    }
    ushort_t hi = f2b(v);
    TWh[d] = hi;
    TWl[d] = f2b(v - b2f(hi));
  }
}

// lift + zero-pad; H pixel-major [b][px][c] bf16
__global__ __launch_bounds__(256) void k_lift(const float* __restrict__ xin, const float* __restrict__ lw,
                                              const float* __restrict__ lb, ushort_t* __restrict__ H){
  int t = threadIdx.x, b = blockIdx.y;
  int px = blockIdx.x*4 + (t>>6);
  int c  = t & 63;
  int x = px / PH, y = px - x*PH;
  float v = 0.f;
  if (x < 256 && y < 256) v = lw[c]*xin[((size_t)(b*256+x))*256 + y] + lb[c];
  H[((size_t)b*NPIX + px)*64 + c] = f2b(v);
}

// fwd DFT along y: tmp[b][x][kk][c] = sum_y H[b][x*264+y][c] * tFT[y][kk]
__global__ __launch_bounds__(256) void k_fwd_y(const ushort_t* __restrict__ H, const float* __restrict__ tFT,
                                               float* __restrict__ tmp){
  int t = threadIdx.x;
  int row = blockIdx.x*4 + (t>>6);        // 0..4223 = b*264+x
  int c = t & 63;
  int b = row / 264, x = row - b*264;
  const ushort_t* hp = H + ((size_t)b*NPIX + (size_t)x*PH)*64 + c;
  float acc[32];
#pragma unroll
  for (int j=0;j<32;++j) acc[j]=0.f;
  for (int y=0; y<PH; ++y){
    float h = b2f(hp[(size_t)y*64]);
    const float* fr = tFT + y*32;         // wave-uniform
#pragma unroll
    for (int j=0;j<32;++j) acc[j] += h*fr[j];
  }
  float* op = tmp + (((size_t)row)*32)*64 + c;
#pragma unroll
  for (int j=0;j<32;++j) op[(size_t)j*64] = acc[j];
}

// fwd DFT along x: Xf[img=(b*64+c)][m] = sum_x tmp[b][x][ky-pair][c] * e^{-i..}
__global__ __launch_bounds__(256) void k_fwd_x(const float* __restrict__ tmp, const float* __restrict__ tCT,
                                               const float* __restrict__ tST, float* __restrict__ Xf){
  int t = threadIdx.x, b = blockIdx.y;
  int m = blockIdx.x*4 + (t>>6);          // 0..511
  int c = t & 63;
  int kxi = m >> 4, ky = m & 15;
  float xr=0.f, xi=0.f;
  const float* base = tmp + ((size_t)b*264*32 + 2*ky)*64 + c;
  for (int x=0; x<PH; ++x){
    float tr = base[(size_t)x*32*64];
    float ti = base[(size_t)x*32*64 + 64];
    float cc = tCT[x*32+kxi], ss = tST[x*32+kxi];   // wave-uniform
    xr += tr*cc + ti*ss;
    xi += ti*cc - tr*ss;
  }
  ((float2*)Xf)[(size_t)(b*64+c)*512 + m] = make_float2(xr, xi);
}

// per-mode 64x64 complex channel mix (unchanged)
__global__ __launch_bounds__(512) void k_mix(const float* __restrict__ Xf, const float* __restrict__ w1,
                                             const float* __restrict__ w2, float* __restrict__ oft){
  int m = threadIdx.x;
  int o = blockIdx.x;
  int b0 = blockIdx.y*4;
  const float2* X = (const float2*)Xf;
  const float2* W = (const float2*)((m < 256) ? w1 : w2);
  int mm = m & 255;
  float2 acc[4];
#pragma unroll
  for (int b=0;b<4;++b) acc[b] = make_float2(0.f,0.f);
  for (int i=0;i<64;++i){
    float2 w = W[(size_t)(i*64+o)*256 + mm];
#pragma unroll
    for (int b=0;b<4;++b){
      float2 x = X[((size_t)((b0+b)*64+i)*512) + m];
      acc[b].x += x.x*w.x - x.y*w.y;
      acc[b].y += x.x*w.y + x.y*w.x;
    }
  }
  float2* O = (float2*)oft;
#pragma unroll
  for (int b=0;b<4;++b) O[((size_t)((b0+b)*64+o)*512) + m] = acc[b];
}

// GroupNorm stats from oft via Parseval (unchanged)
__global__ __launch_bounds__(256) void k_stats_spec(const float* __restrict__ oft, float2* __restrict__ stats){
  __shared__ float sq[256], s1s[256];
  int bg = blockIdx.x, t = threadIdx.x;
  int b = bg >> 2, g = bg & 3;
  const float2* O = (const float2*)oft;
  float q = 0.f, s1 = 0.f;
  for (int c16=0; c16<16; ++c16){
    const float2* Op = O + (size_t)(b*64 + g*16 + c16)*512;
    for (int m=t; m<512; m+=256){
      if (m & 15){ float2 v = Op[m]; q += 2.f*(v.x*v.x + v.y*v.y); }
    }
  }
  {
    int c16 = t >> 4, j = t & 15;
    const float2* Op = O + (size_t)(b*64 + g*16 + c16)*512;
    if (j == 0){
      float2 a0 = Op[0];
      s1 = a0.x;
      q += a0.x*a0.x;
      float2 h16 = Op[16*16];
      q += 0.5f*(h16.x*h16.x + h16.y*h16.y);
    } else {
      float2 a = Op[j*16];
      float2 bb = Op[(32-j)*16];
      float rr = a.x + bb.x, ii = a.y - bb.y;
      q += 0.5f*(rr*rr + ii*ii);
    }
  }
  sq[t] = q; s1s[t] = s1; __syncthreads();
  for (int st_=128; st_>0; st_>>=1){
    if (t < st_){ sq[t] += sq[t+st_]; s1s[t] += s1s[t+st_]; }
    __syncthreads();
  }
  if (t == 0){
    const float invN = 1.0f/1115136.0f;
    float mu  = s1s[0]*invN;
    float ssq = sq[0]*(1.0f/69696.0f);
    float var = fmaxf(ssq*invN - mu*mu, 0.f);
    stats[bg] = make_float2(mu, 1.0f/sqrtf(var + 1e-5f));
  }
}

// inverse DFT along x (unchanged): z[img=(b*64+c)][x][kk]
__global__ __launch_bounds__(256) void k_inv_x(const float* __restrict__ oft, const float* __restrict__ tCT,
                                               const float* __restrict__ tST, float* __restrict__ z){
  __shared__ float sof[1024];
  int t = threadIdx.x, img = blockIdx.x;
  const float* op = oft + (size_t)img*1024;
  for (int d=t; d<1024; d+=256) sof[d] = op[d];
  __syncthreads();
  for (int x=t; x<264; x+=256){
    float zr[16], zi[16];
#pragma unroll
    for (int k=0;k<16;++k){ zr[k]=0.f; zi[k]=0.f; }
    for (int kxi=0; kxi<32; ++kxi){
      float c = tCT[x*32+kxi], s = tST[x*32+kxi];
#pragma unroll
      for (int ky=0; ky<16; ++ky){
        float orr = sof[(kxi*16+ky)*2], oii = sof[(kxi*16+ky)*2 + 1];
        zr[ky] += orr*c - oii*s;
        zi[ky] += oii*c + orr*s;
      }
    }
    float* zp = z + ((size_t)img*264 + x)*32;
#pragma unroll
    for (int k=0;k<16;++k){ zp[2*k] = zr[k]; zp[2*k+1] = zi[k]; }
  }
}

// Row-tile MFMA fused layer: H(new) = gelu( TW·(z·alpha) + H·Wconv + beta ), in place on H.
// grid (264 x-rows, 16 b); 256 thr (4 waves); wave w owns m-tiles {w,w+4,w+8,w+12,(16 if w==0)}.
// A(spec) = TWg hi/lo direct from global (L2-hot); A(conv) = H row direct from global.
// B(spec) = zB hi/lo in LDS; B(conv) = cw bf16 in LDS.  LDS = 19.4 KB.
__global__ __launch_bounds__(256, 4) void k_fused2(ushort_t* __restrict__ H, const float* __restrict__ z,
                                                const float* __restrict__ cw, const float* __restrict__ cb,
                                                const float* __restrict__ gg, const float* __restrict__ gb,
                                                const float2* __restrict__ stats,
                                                const ushort_t* __restrict__ TWh, const ushort_t* __restrict__ TWl,
                                                int do_gelu){
  __shared__ short zBh[64*40], zBl[64*40];   // (z*alpha)^T [o][kk] hi/lo, stride 40
  __shared__ short cwL[64*72];               // bf16 conv weights [o][i], stride 72 (16B aligned)
  int t = threadIdx.x, b = blockIdx.y, x = blockIdx.x;

  // build zB (one x-row) and cwL
  for (int d=t; d<2048; d+=256){
    int o = d>>5, k = d&31;
    float al = stats[b*4 + (o>>4)].y * gg[o] * (2.0f/69696.0f);
    float v = z[((size_t)(b*64+o)*PH + x)*32 + k] * al;
    ushort_t hi = f2b(v);
    zBh[o*40+k] = (short)hi;
    zBl[o*40+k] = (short)f2b(v - b2f(hi));
  }
  for (int d=t; d<4096; d+=256){
    int o = d>>6, i = d&63;
    cwL[o*72+i] = (short)f2b(cw[o*64+i]);
  }
  __syncthreads();

  int w = t >> 6, lane = t & 63;
  int quad = lane >> 4, lcol = lane & 15;

  float4v acc[5][4];
#pragma unroll
  for (int si=0;si<5;++si)
#pragma unroll
    for (int n=0;n<4;++n) acc[si][n] = (float4v){0.f,0.f,0.f,0.f};

#pragma unroll
  for (int si=0;si<5;++si){
    int mt = w + 4*si;
    if (mt > 16) break;                       // wave-uniform
    int pxl = mt*16 + lcol;                   // local px (row y) 0..271
    union{uint4 u; short8 s;} a0, a1;
    a0.u = make_uint4(0,0,0,0); a1.u = make_uint4(0,0,0,0);
    if (pxl < PH){
      const ushort_t* hp = H + ((size_t)b*NPIX + (size_t)x*PH + pxl)*64 + quad*8;
      a0.u = *(const uint4*)hp;
      a1.u = *(const uint4*)(hp + 32);
    }
    short8 Th = *(const short8*)(TWh + pxl*32 + quad*8);
    short8 Tl = *(const short8*)(TWl + pxl*32 + quad*8);
#pragma unroll
    for (int n=0;n<4;++n){
      float4v a = acc[si][n];
      short8 Bc0 = *(const short8*)&cwL[(n*16+lcol)*72 + quad*8];
      short8 Bc1 = *(const short8*)&cwL[(n*16+lcol)*72 + 32 + quad*8];
      a = __builtin_amdgcn_mfma_f32_16x16x32_bf16(a0.s, Bc0, a, 0, 0, 0);
      a = __builtin_amdgcn_mfma_f32_16x16x32_bf16(a1.s, Bc1, a, 0, 0, 0);
      short8 Bzh = *(const short8*)&zBh[(n*16+lcol)*40 + quad*8];
      short8 Bzl = *(const short8*)&zBl[(n*16+lcol)*40 + quad*8];
      a = __builtin_amdgcn_mfma_f32_16x16x32_bf16(Th, Bzh, a, 0, 0, 0);
      a = __builtin_amdgcn_mfma_f32_16x16x32_bf16(Th, Bzl, a, 0, 0, 0);
      a = __builtin_amdgcn_mfma_f32_16x16x32_bf16(Tl, Bzh, a, 0, 0, 0);
      acc[si][n] = a;
    }
  }

  // epilogue: + (gb - mu*rstd*g + cb), gelu, store bf16
#pragma unroll
  for (int n=0;n<4;++n){
    int o = n*16 + lcol;
    float2 st = stats[b*4 + n];
    float beta = gb[o] - st.x*st.y*gg[o] + cb[o];
#pragma unroll
    for (int si=0;si<5;++si){
      int mt = w + 4*si;
      if (mt > 16) break;
#pragma unroll
      for (int reg=0; reg<4; ++reg){
        int pxl = mt*16 + quad*4 + reg;
        if (pxl < PH){
          float v = acc[si][n][reg] + beta;
          if (do_gelu) v = gelu_f(v);
          H[((size_t)b*NPIX + (size_t)x*PH + pxl)*64 + o] = f2b(v);
        }
      }
    }
  }
}

// decoder: crop -> dec1 -> gelu -> dec2 (pixel-major H read)
__global__ __launch_bounds__(256) void k_dec(const ushort_t* __restrict__ H, const float* __restrict__ w1,
                                             const float* __restrict__ b1, const float* __restrict__ w2,
                                             const float* __restrict__ b2, float* __restrict__ out){
  __shared__ float w1L[4096];
  __shared__ float w2L[64], b1L[64];
  int t = threadIdx.x, x = blockIdx.x, b = blockIdx.y;
  for (int d=t; d<4096; d+=256) w1L[d] = w1[d];
  if (t < 64){ w2L[t] = w2[t]; b1L[t] = b1[t]; }
  __syncthreads();
  const ushort_t* hp = H + ((size_t)b*NPIX + (size_t)x*PH + t)*64;
  float hv[64];
#pragma unroll
  for (int q=0;q<8;++q){
    uint4 u = *(const uint4*)(hp + q*8);
    hv[q*8+0] = blo(u.x); hv[q*8+1] = bhi(u.x);
    hv[q*8+2] = blo(u.y); hv[q*8+3] = bhi(u.y);
    hv[q*8+4] = blo(u.z); hv[q*8+5] = bhi(u.z);
    hv[q*8+6] = blo(u.w); hv[q*8+7] = bhi(u.w);
  }
  float oacc = 0.f;
  for (int o=0;o<64;++o){
    float a = b1L[o];
#pragma unroll
    for (int c=0;c<64;++c) a += w1L[o*64+c]*hv[c];
    a = gelu_f(a);
    oacc += w2L[o]*a;
  }
  out[((size_t)b*256 + x)*256 + t] = oacc + b2[0];
}

extern "C" void kernel_launch(void* const* d_in, const int* in_sizes, int n_in,
                              void* d_out, int out_size, void* d_ws, size_t ws_size,
                              hipStream_t stream){
  const float* x    = (const float*)d_in[0];
  const float* liw  = (const float*)d_in[1];
  const float* lib  = (const float*)d_in[2];
  const float* w1   = (const float*)d_in[3];
  const float* w2   = (const float*)d_in[4];
  const float* cw   = (const float*)d_in[5];
  const float* cb   = (const float*)d_in[6];
  const float* gg   = (const float*)d_in[7];
  const float* gb   = (const float*)d_in[8];
  const float* dw1  = (const float*)d_in[9];
  const float* db1  = (const float*)d_in[10];
  const float* dw2  = (const float*)d_in[11];
  const float* db2  = (const float*)d_in[12];
  float* out = (float*)d_out;

  // ws: H 142.7MB bf16 (pixel-major) | tmp 138MB f32 | Xf 4.2MB | oft 4.2MB | tables | stats  ~= 186 MB
  char* p = (char*)d_ws;
  ushort_t* H = (ushort_t*)p; p += (size_t)NBAT*NPIX*64*2;
  float* tmp  = (float*)p; p += (size_t)NBAT*264*32*64*4;
  float* Xf   = (float*)p; p += (size_t)NIMG*512*2*4;
  float* oft  = (float*)p; p += (size_t)NIMG*512*2*4;
  float* tFT  = (float*)p; p += 8448*4;
  float* tCT  = (float*)p; p += 8448*4;
  float* tST  = (float*)p; p += 8448*4;
  float* tYc  = (float*)p; p += 4224*4;
  float* tYs  = (float*)p; p += 4224*4;
  ushort_t* TWh = (ushort_t*)p; p += 8704*2;
  ushort_t* TWl = (ushort_t*)p; p += 8704*2;
  float2* stats = (float2*)p; p += 64*8;

  k_tables<<<132, 256, 0, stream>>>(tFT, tCT, tST, tYc, tYs, TWh, TWl);
  k_lift<<<dim3(NPIX/4, 16), 256, 0, stream>>>(x, liw, lib, H);

  for (int k=0;k<NLAY;++k){
    k_fwd_y<<<1056, 256, 0, stream>>>(H, tFT, tmp);
    k_fwd_x<<<dim3(128,16), 256, 0, stream>>>(tmp, tCT, tST, Xf);
    k_mix<<<dim3(64,4), 512, 0, stream>>>(Xf, w1 + (size_t)k*2097152, w2 + (size_t)k*2097152, oft);
    k_stats_spec<<<64, 256, 0, stream>>>(oft, stats);
    k_inv_x<<<1024, 256, 0, stream>>>(oft, tCT, tST, tmp);
    k_fused2<<<dim3(264,16), 256, 0, stream>>>(H, tmp, cw + (size_t)k*4096, cb + (size_t)k*64,
                                               gg + (size_t)k*64, gb + (size_t)k*64, stats, TWh, TWl, (k<3)?1:0);
  }
  k_dec<<<dim3(256,16), 256, 0, stream>>>(H, dw1, db1, dw2, db2, out);
}